// Round 1
// baseline (361.206 us; speedup 1.0000x reference)
//
#include <hip/hip_runtime.h>
#include <stdint.h>

#define B_ 8
#define C_ 256
#define N_ 4096
#define M_ 4096
#define NT 64
#define MT 64
#define PP 72    // sP pitch (64 + 8 pad) halves; 144B rows
#define L2E 1.44269504f

typedef _Float16 f16x8 __attribute__((ext_vector_type(8)));
typedef _Float16 f16x4 __attribute__((ext_vector_type(4)));
typedef float f32x4 __attribute__((ext_vector_type(4)));

__device__ __forceinline__ void async16(const _Float16* g, _Float16* l) {
    __builtin_amdgcn_global_load_lds(
        (const __attribute__((address_space(1))) void*)g,
        (__attribute__((address_space(3))) void*)l, 16, 0, 0);
}

// fused pre-pass: blocks [0,2048) transpose xs -> kt [B,M,C] fp16;
//                 blocks [2048,10240) convert ys -> vb [B,C,M] fp16
__global__ __launch_bounds__(256) void kPre(const float* __restrict__ xs,
                                            const float* __restrict__ ys,
                                            _Float16* __restrict__ kt,
                                            _Float16* __restrict__ vb) {
    int bx = blockIdx.x;
    int t = threadIdx.x;
    if (bx < 2048) {
        __shared__ float tile[64][65];
        int b = bx >> 8, rem = bx & 255;
        int c0 = (rem >> 6) * 64, m0 = (rem & 63) * 64;
        int cl = t >> 4, m4 = (t & 15) * 4;
#pragma unroll
        for (int i = 0; i < 4; i++) {
            int c = c0 + cl + i * 16;
            const float4 v = *(const float4*)(xs + ((size_t)(b * C_ + c) * M_) + m0 + m4);
            tile[m4 + 0][cl + i * 16] = v.x;
            tile[m4 + 1][cl + i * 16] = v.y;
            tile[m4 + 2][cl + i * 16] = v.z;
            tile[m4 + 3][cl + i * 16] = v.w;
        }
        __syncthreads();
        int ml = t >> 4, c4 = (t & 15) * 4;
#pragma unroll
        for (int i = 0; i < 4; i++) {
            int m = m0 + ml + i * 16;
            f16x4 o;
            o[0] = (_Float16)tile[ml + i * 16][c4 + 0];
            o[1] = (_Float16)tile[ml + i * 16][c4 + 1];
            o[2] = (_Float16)tile[ml + i * 16][c4 + 2];
            o[3] = (_Float16)tile[ml + i * 16][c4 + 3];
            *(f16x4*)(kt + ((size_t)(b * M_ + m) * C_) + c0 + c4) = o;
        }
    } else {
        size_t i = ((size_t)(bx - 2048) * 256 + t) * 4;
        float4 v = *(const float4*)(ys + i);
        f16x4 o;
        o[0] = (_Float16)v.x; o[1] = (_Float16)v.y;
        o[2] = (_Float16)v.z; o[3] = (_Float16)v.w;
        *(f16x4*)(vb + i) = o;
    }
}

// flash-attention: one block per (batch, 64-query tile), 2 blocks/CU
// Swapped QK^T: S^T = mfma(K_frag, Q_frag) so each lane owns one n-row's
// m-values -> in-register softmax (2 shuffles), vectorized P stores.
// Raw barriers with targeted waitcnt: K prefetch stays in flight across
// barrier B (only lgkmcnt drained), drained only at barrier A.
__global__ __launch_bounds__(256, 2) void kAttn(const float* __restrict__ h,
                                                const _Float16* __restrict__ kt,
                                                const _Float16* __restrict__ vb,
                                                float* __restrict__ out) {
    // sK[buf]: [row][256] fp16, 16B chunks XOR-swizzled by (row&31). sK[1] holds Q in prologue.
    __shared__ _Float16 sK[2][MT * 256];     // 64 KB
    __shared__ _Float16 sP[NT * PP];         // 9.2 KB
    __shared__ float sAlpha[NT];
    __shared__ float sL[NT];
    __shared__ int sFlag[2];

    const int t = threadIdx.x;
    const int w = t >> 6, lane = t & 63, quad = lane >> 4, l15 = lane & 15;
    const int b = blockIdx.x >> 6;
    const int n0 = (blockIdx.x & 63) * NT;
    const int nb = w * 16;   // wave's n strip (S^T cols / P rows)
    const int cb = w * 64;   // wave's O-channel strip

    const _Float16* srcKb = kt + (size_t)b * M_ * C_;
    const _Float16* srcVb = vb + (size_t)b * C_ * M_;

    if (t == 0) { sFlag[0] = 0; sFlag[1] = 0; }

    // ---- stage Q (transposed+swizzled) into sK[1]; issue K tile 0 into sK[0] ----
    {
        int cl = t >> 4, n4 = (t & 15) * 4;
        for (int i = 0; i < 16; i++) {
            int c = i * 16 + cl;
            const float4 v = *(const float4*)(h + ((size_t)(b * C_ + c) * N_) + n0 + n4);
            float xv[4] = {v.x, v.y, v.z, v.w};
#pragma unroll
            for (int j = 0; j < 4; j++) {
                int row = n4 + j;
                sK[1][row * 256 + (((c >> 3) ^ (row & 31)) << 3) + (c & 7)] = (_Float16)xv[j];
            }
        }
#pragma unroll
        for (int j = 0; j < 8; j++) {
            int row = w * 16 + j * 2 + (lane >> 5);
            int logi = (lane & 31) ^ (row & 31);
            async16(srcKb + (size_t)row * C_ + logi * 8, &sK[0][(w * 16 + j * 2) * 256]);
        }
    }
    // Q ds_writes visible to all waves; K0 vmcnt NOT drained (overlaps qf reads)
    asm volatile("s_waitcnt lgkmcnt(0)" ::: "memory");
    __builtin_amdgcn_s_barrier();

    // ---- Q fragments to registers (B-operand of swapped MFMA; same read pattern) ----
    f16x8 qf[8];
    {
        int qrow = nb + l15;
#pragma unroll
        for (int ks = 0; ks < 8; ks++)
            qf[ks] = *(const f16x8*)(&sK[1][qrow * 256 + ((((ks << 2) + quad) ^ (qrow & 31)) << 3)]);
    }
    // qf must be in regs before iter-0's prefetch overwrites sK[1]
    asm volatile("s_waitcnt lgkmcnt(0)" ::: "memory");

    f32x4 o[4][4];
#pragma unroll
    for (int i = 0; i < 4; i++)
#pragma unroll
        for (int j = 0; j < 4; j++)
            o[i][j] = (f32x4){0.f, 0.f, 0.f, 0.f};

    float mst = -3.0e38f, lp = 0.f;

    for (int it = 0; it < M_ / MT; it++) {
        const int cur = it & 1, nxt = cur ^ 1;
        const int m0i = it * MT;
        // barrier A: K(it) prefetch landed (own vmcnt(0) + barrier => all waves' loads in LDS)
        asm volatile("s_waitcnt vmcnt(0)" ::: "memory");
        __builtin_amdgcn_s_barrier();

        if (t == 0) sFlag[nxt] = 0;   // armed for iteration it+1

        // V fragments FIRST (oldest vmem => PV's wait leaves K prefetch in flight)
        f16x8 vf[2][4];
#pragma unroll
        for (int ks = 0; ks < 2; ks++)
#pragma unroll
            for (int ct = 0; ct < 4; ct++) {
                int vrow = cb + ct * 16 + l15;
                vf[ks][ct] = *(const f16x8*)(srcVb + (size_t)vrow * M_ + m0i + ks * 32 + quad * 8);
            }
        __builtin_amdgcn_sched_barrier(0);   // pin V-issue before K-issue

        // issue K-(it+1) into the buffer S-(it-1) just finished reading
        if (it + 1 < M_ / MT) {
            const _Float16* srcK = srcKb + (size_t)(m0i + MT) * C_;
#pragma unroll
            for (int j = 0; j < 8; j++) {
                int row = w * 16 + j * 2 + (lane >> 5);
                int logi = (lane & 31) ^ (row & 31);
                async16(srcK + (size_t)row * C_ + logi * 8, &sK[nxt][(w * 16 + j * 2) * 256]);
            }
        }

        // ---- S^T = K·Q^T : rows m=[0,64), cols n = wave strip [nb,nb+16) ----
        // s[mt][r] = S^T[m = mt*16 + quad*4 + r][n = nb + l15]
        f32x4 s[4];
#pragma unroll
        for (int mt = 0; mt < 4; mt++) s[mt] = (f32x4){0.f, 0.f, 0.f, 0.f};
        __builtin_amdgcn_s_setprio(1);
#pragma unroll
        for (int ks = 0; ks < 8; ks++) {
#pragma unroll
            for (int mt = 0; mt < 4; mt++) {
                int krow = mt * 16 + l15;
                f16x8 bk = *(const f16x8*)(&sK[cur][krow * 256 + ((((ks << 2) + quad) ^ (krow & 31)) << 3)]);
                s[mt] = __builtin_amdgcn_mfma_f32_16x16x32_f16(bk, qf[ks], s[mt], 0, 0, 0);
            }
        }
        __builtin_amdgcn_s_setprio(0);

        // ---- in-register online softmax for this lane's row n = nb+l15 ----
        float rowmax = fmaxf(fmaxf(fmaxf(s[0][0], s[0][1]), fmaxf(s[0][2], s[0][3])),
                             fmaxf(fmaxf(s[1][0], s[1][1]), fmaxf(s[1][2], s[1][3])));
        rowmax = fmaxf(rowmax, fmaxf(fmaxf(fmaxf(s[2][0], s[2][1]), fmaxf(s[2][2], s[2][3])),
                                     fmaxf(fmaxf(s[3][0], s[3][1]), fmaxf(s[3][2], s[3][3]))));
        rowmax = fmaxf(rowmax, __shfl_xor(rowmax, 16, 64));
        rowmax = fmaxf(rowmax, __shfl_xor(rowmax, 32, 64));
        float al = 1.0f;
        if (rowmax > mst) {
            al = exp2f((mst - rowmax) * L2E);
            mst = rowmax;
        }
        const float mb = mst * L2E;
        float psum = 0.f;
#pragma unroll
        for (int mt = 0; mt < 4; mt++)
#pragma unroll
            for (int r = 0; r < 4; r++) {
                float p = exp2f(s[mt][r] * L2E - mb);
                s[mt][r] = p;
                psum += p;
            }
        lp = lp * al + psum;
        if (quad == 0) {
            sAlpha[nb + l15] = al;
            if (al != 1.0f) atomicOr(&sFlag[cur], 1);
        }
        // vectorized P store: consecutive r = consecutive m
#pragma unroll
        for (int mt = 0; mt < 4; mt++) {
            f16x4 pk;
            pk[0] = (_Float16)s[mt][0];
            pk[1] = (_Float16)s[mt][1];
            pk[2] = (_Float16)s[mt][2];
            pk[3] = (_Float16)s[mt][3];
            *(f16x4*)(&sP[(nb + l15) * PP + mt * 16 + quad * 4]) = pk;
        }

        // barrier B: P + alphas + flag visible; vmcnt NOT drained (K prefetch flies on)
        asm volatile("s_waitcnt lgkmcnt(0)" ::: "memory");
        __builtin_amdgcn_s_barrier();

        // ---- rescale O only if some row's max moved this tile ----
        if (sFlag[cur]) {
            float av[4];
#pragma unroll
            for (int nt = 0; nt < 4; nt++) av[nt] = sAlpha[nt * 16 + l15];
#pragma unroll
            for (int ct = 0; ct < 4; ct++)
#pragma unroll
                for (int nt = 0; nt < 4; nt++) {
                    o[ct][nt][0] *= av[nt];
                    o[ct][nt][1] *= av[nt];
                    o[ct][nt][2] *= av[nt];
                    o[ct][nt][3] *= av[nt];
                }
        }

        // ---- O += V·P^T ----
        __builtin_amdgcn_s_setprio(1);
#pragma unroll
        for (int ks = 0; ks < 2; ks++) {
#pragma unroll
            for (int nt = 0; nt < 4; nt++) {
                f16x8 bp = *(const f16x8*)(sP + (nt * 16 + l15) * PP + ks * 32 + quad * 8);
#pragma unroll
                for (int ct = 0; ct < 4; ct++)
                    o[ct][nt] = __builtin_amdgcn_mfma_f32_16x16x32_f16(vf[ks][ct], bp, o[ct][nt], 0, 0, 0);
            }
        }
        __builtin_amdgcn_s_setprio(0);
    }

    // ---- epilogue: finish deferred l across quads, divide, store ----
    lp += __shfl_xor(lp, 16, 64);
    lp += __shfl_xor(lp, 32, 64);
    if (quad == 0) sL[nb + l15] = lp;
    __syncthreads();
    float linv[4];
#pragma unroll
    for (int nt = 0; nt < 4; nt++) linv[nt] = 1.0f / sL[nt * 16 + l15];
#pragma unroll
    for (int ct = 0; ct < 4; ct++)
#pragma unroll
        for (int nt = 0; nt < 4; nt++)
#pragma unroll
            for (int r = 0; r < 4; r++) {
                int c = cb + ct * 16 + quad * 4 + r;
                out[((size_t)(b * C_ + c)) * N_ + n0 + nt * 16 + l15] = o[ct][nt][r] * linv[nt];
            }
}

extern "C" void kernel_launch(void* const* d_in, const int* in_sizes, int n_in,
                              void* d_out, int out_size, void* d_ws, size_t ws_size,
                              hipStream_t stream) {
    const float* h  = (const float*)d_in[0];
    const float* xs = (const float*)d_in[1];
    const float* ys = (const float*)d_in[2];
    float* out = (float*)d_out;

    _Float16* kt  = (_Float16*)d_ws;                    // [B,M,C] fp16: 16 MB
    _Float16* vbb = kt + (size_t)B_ * M_ * C_;          // [B,C,M] fp16: 16 MB

    kPre<<<dim3(2048 + 8192), 256, 0, stream>>>(xs, ys, kt, vbb);
    kAttn<<<dim3(B_ * (N_ / NT)), 256, 0, stream>>>(h, kt, vbb, out);
}